// Round 9
// baseline (406.246 us; speedup 1.0000x reference)
//
#include <hip/hip_runtime.h>
#include <math.h>

// GPT-2 block. B=8 T=1024 C=768 H=8 D=96. M = B*T = 8192.
// GEMMs + attention in fp16 MFMA (fp32 accum/softmax), LN/epilogues fp32.
// R7: fast GELU epilogue (tanh via hardware __expf identity) — removes the
//     ~50 us VALU-critical-path tanhf in the fc GEMM.

#define MROWS 8192
#define CDIM  768
#define TSEQ  1024

typedef _Float16 f16x8 __attribute__((ext_vector_type(8)));
typedef _Float16 f16x4 __attribute__((ext_vector_type(4)));
typedef float f32x4 __attribute__((ext_vector_type(4)));

__device__ __forceinline__ void async_copy16(void* lds, const void* g) {
    __builtin_amdgcn_global_load_lds(
        (const __attribute__((address_space(1))) unsigned int*)g,
        (__attribute__((address_space(3))) unsigned int*)lds, 16, 0, 0);
}

// bijective XCD-aware swizzle of the linear workgroup id (m204 form)
__device__ __forceinline__ int xcd_swizzle(int orig, int nwg) {
    int q = nwg >> 3, r = nwg & 7;
    int xcd = orig & 7, lid = orig >> 3;
    return (xcd < r ? xcd * (q + 1) : r * (q + 1) + (xcd - r) * q) + lid;
}

// GELU (tanh form) with tanh(u) = 1 - 2/(exp(2u)+1); exact limits at +-inf.
__device__ __forceinline__ float fast_gelu(float u) {
    float inner = 0.7978845608028654f * (u + 0.044715f * u * u * u);
    float e = __expf(2.0f * inner);
    float th = 1.0f - 2.0f / (e + 1.0f);
    return 0.5f * u * (1.0f + th);
}

// ------------- fused fp32 -> fp16 convert for all 4 weights -------------
__global__ __launch_bounds__(256) void f2h4_kernel(const float* __restrict__ i0,
                                                   const float* __restrict__ i1,
                                                   const float* __restrict__ i2,
                                                   const float* __restrict__ i3,
                                                   _Float16* __restrict__ o0,
                                                   _Float16* __restrict__ o1,
                                                   _Float16* __restrict__ o2,
                                                   _Float16* __restrict__ o3) {
    int bb = blockIdx.x;
    const float* in;
    _Float16* out;
    int lb;
    if (bb < 432)       { in = i0; out = o0; lb = bb; }
    else if (bb < 576)  { in = i1; out = o1; lb = bb - 432; }
    else if (bb < 1152) { in = i2; out = o2; lb = bb - 576; }
    else                { in = i3; out = o3; lb = bb - 1152; }
    int i = lb * 1024 + threadIdx.x;
#pragma unroll
    for (int p = 0; p < 4; ++p, i += 256) {
        float4 v = reinterpret_cast<const float4*>(in)[i];
        f16x4 h;
        h[0] = (_Float16)v.x; h[1] = (_Float16)v.y;
        h[2] = (_Float16)v.z; h[3] = (_Float16)v.w;
        reinterpret_cast<f16x4*>(out)[i] = h;
    }
}

// ---------------- LayerNorm -> fp16 out ----------------
__global__ __launch_bounds__(256) void ln_kernel(const float* __restrict__ x,
                                                 const float* __restrict__ g,
                                                 const float* __restrict__ bta,
                                                 _Float16* __restrict__ out) {
    int row = blockIdx.x;
    int t = threadIdx.x;
    const float* xr = x + (size_t)row * CDIM;
    float v0 = xr[t], v1 = xr[t + 256], v2 = xr[t + 512];
    float s = v0 + v1 + v2;
    float q = v0 * v0 + v1 * v1 + v2 * v2;
#pragma unroll
    for (int o = 32; o; o >>= 1) {
        s += __shfl_xor(s, o);
        q += __shfl_xor(q, o);
    }
    __shared__ float ls[4], lq[4];
    int w = t >> 6, lane = t & 63;
    if (lane == 0) { ls[w] = s; lq[w] = q; }
    __syncthreads();
    s = ls[0] + ls[1] + ls[2] + ls[3];
    q = lq[0] + lq[1] + lq[2] + lq[3];
    float mean = s * (1.0f / CDIM);
    float var = fmaxf(q * (1.0f / CDIM) - mean * mean, 0.0f);
    float rstd = rsqrtf(var + 1e-5f);
    _Float16* orow = out + (size_t)row * CDIM;
    orow[t]       = (_Float16)((v0 - mean) * rstd * g[t]       + bta[t]);
    orow[t + 256] = (_Float16)((v1 - mean) * rstd * g[t + 256] + bta[t + 256]);
    orow[t + 512] = (_Float16)((v2 - mean) * rstd * g[t + 512] + bta[t + 512]);
}

// ---------------- fp16 MFMA GEMM (m97 structure, BM=128) ----------------
template <int EPI, typename OutT>  // EPI 0: bias, 1: bias+res, 2: bias+gelu
__global__ __launch_bounds__(256) void hgemm(const _Float16* __restrict__ A,
                                             const _Float16* __restrict__ W,
                                             const float* __restrict__ bias,
                                             const float* __restrict__ res,
                                             OutT* __restrict__ out,
                                             int M, int N, int K) {
    __shared__ _Float16 As[128 * 32];
    __shared__ _Float16 Bs[128 * 32];
    const int t = threadIdx.x;
    const int wid = t >> 6;
    const int l = t & 63;
    const int fr = l & 15;
    const int fq = l >> 4;
    const int wr = wid >> 1, wc = wid & 1;

    const int nx = gridDim.x;
    const int wg = xcd_swizzle(blockIdx.y * nx + blockIdx.x, nx * gridDim.y);
    const int row0 = (wg / nx) * 128, col0 = (wg % nx) * 128;

    const _Float16* ga = A + (size_t)row0 * K;
    const _Float16* gb = W + (size_t)col0 * K;

    f32x4 acc[4][4] = {};
    const int r_st = t >> 2, c_st = (t & 3) * 8;

    for (int k0 = 0; k0 < K; k0 += 32) {
        __syncthreads();
#pragma unroll
        for (int p = 0; p < 2; ++p) {
            char* la = (char*)As + wid * 1024 + p * 4096;
            char* lb = (char*)Bs + wid * 1024 + p * 4096;
            int r = r_st + p * 64;
            async_copy16(la, ga + (size_t)r * K + k0 + c_st);
            async_copy16(lb, gb + (size_t)r * K + k0 + c_st);
        }
        __syncthreads();

        f16x8 af[4], bf[4];
#pragma unroll
        for (int m = 0; m < 4; ++m)
            af[m] = *reinterpret_cast<const f16x8*>(&As[(wr * 64 + m * 16 + fr) * 32 + fq * 8]);
#pragma unroll
        for (int n = 0; n < 4; ++n)
            bf[n] = *reinterpret_cast<const f16x8*>(&Bs[(wc * 64 + n * 16 + fr) * 32 + fq * 8]);
#pragma unroll
        for (int m = 0; m < 4; ++m)
#pragma unroll
            for (int n = 0; n < 4; ++n)
                acc[m][n] = __builtin_amdgcn_mfma_f32_16x16x32_f16(af[m], bf[n], acc[m][n], 0, 0, 0);
    }

#pragma unroll
    for (int m = 0; m < 4; ++m) {
#pragma unroll
        for (int j = 0; j < 4; ++j) {
            int r = row0 + wr * 64 + m * 16 + fq * 4 + j;
#pragma unroll
            for (int n = 0; n < 4; ++n) {
                int c = col0 + wc * 64 + n * 16 + fr;
                float v = acc[m][n][j] + bias[c];
                if (EPI == 1) v += res[(size_t)r * N + c];
                if (EPI == 2) v = fast_gelu(v);
                out[(size_t)r * N + c] = (OutT)v;
            }
        }
    }
}

// ------- fp16 MFMA GEMM, BM=64 (grid-limited N=768 GEMMs: 12 waves/CU) -------
template <int EPI, typename OutT>
__global__ __launch_bounds__(256) void hgemm64(const _Float16* __restrict__ A,
                                               const _Float16* __restrict__ W,
                                               const float* __restrict__ bias,
                                               const float* __restrict__ res,
                                               OutT* __restrict__ out,
                                               int M, int N, int K) {
    __shared__ _Float16 As[64 * 32];
    __shared__ _Float16 Bs[128 * 32];
    const int t = threadIdx.x;
    const int wid = t >> 6;
    const int l = t & 63;
    const int fr = l & 15;
    const int fq = l >> 4;
    const int wr = wid >> 1, wc = wid & 1;

    const int nx = gridDim.x;
    const int wg = xcd_swizzle(blockIdx.y * nx + blockIdx.x, nx * gridDim.y);
    const int row0 = (wg / nx) * 64, col0 = (wg % nx) * 128;

    const _Float16* ga = A + (size_t)row0 * K;
    const _Float16* gb = W + (size_t)col0 * K;

    f32x4 acc[2][4] = {};
    const int rl = l >> 2, cl = (l & 3) * 8;

    for (int k0 = 0; k0 < K; k0 += 32) {
        __syncthreads();
        async_copy16((char*)As + wid * 1024, ga + (size_t)(wid * 16 + rl) * K + k0 + cl);
#pragma unroll
        for (int p = 0; p < 2; ++p)
            async_copy16((char*)Bs + wid * 2048 + p * 1024,
                         gb + (size_t)(wid * 32 + p * 16 + rl) * K + k0 + cl);
        __syncthreads();

        f16x8 af[2], bf[4];
#pragma unroll
        for (int m = 0; m < 2; ++m)
            af[m] = *reinterpret_cast<const f16x8*>(&As[(wr * 32 + m * 16 + fr) * 32 + fq * 8]);
#pragma unroll
        for (int n = 0; n < 4; ++n)
            bf[n] = *reinterpret_cast<const f16x8*>(&Bs[(wc * 64 + n * 16 + fr) * 32 + fq * 8]);
#pragma unroll
        for (int m = 0; m < 2; ++m)
#pragma unroll
            for (int n = 0; n < 4; ++n)
                acc[m][n] = __builtin_amdgcn_mfma_f32_16x16x32_f16(af[m], bf[n], acc[m][n], 0, 0, 0);
    }

#pragma unroll
    for (int m = 0; m < 2; ++m) {
#pragma unroll
        for (int j = 0; j < 4; ++j) {
            int r = row0 + wr * 32 + m * 16 + fq * 4 + j;
#pragma unroll
            for (int n = 0; n < 4; ++n) {
                int c = col0 + wc * 64 + n * 16 + fr;
                float v = acc[m][n][j] + bias[c];
                if (EPI == 1) v += res[(size_t)r * N + c];
                if (EPI == 2) v = fast_gelu(v);
                out[(size_t)r * N + c] = (OutT)v;
            }
        }
    }
}

// ---------------- Flash attention, fp16 MFMA ----------------
__global__ __launch_bounds__(256) void attn_kernel(const _Float16* __restrict__ qkv,
                                                   _Float16* __restrict__ y) {
    const int bx = blockIdx.x;  // 0..7
    const int bh = blockIdx.y;
    const int b = bh >> 3, h = bh & 7;
    const int t = threadIdx.x;
    const int wid = t >> 6, l = t & 63;
    const int fr = l & 15, fq = l >> 4;

    __shared__ _Float16 Ks[64 * 104];
    __shared__ _Float16 Vt[96 * 72];
    __shared__ _Float16 Ps[64 * 72];

    const size_t base = (size_t)b * TSEQ * 2304 + h * 96;
    const float scale = 0.10206207261596577f;  // 1/sqrt(96)

    const int kkey = t >> 2, kc = t & 3;
    const int vkey = l, vrow = wid;

    for (int ph = 0; ph < 2; ++ph) {
        const int qt = ph ? (15 - bx) : bx;
        const int q0 = qt * 64;
        const int qrow_g = q0 + wid * 16 + fr;

        f16x8 qa[3];
#pragma unroll
        for (int s = 0; s < 3; ++s)
            qa[s] = *reinterpret_cast<const f16x8*>(
                &qkv[base + (size_t)qrow_g * 2304 + s * 32 + fq * 8]);

        f32x4 O[6] = {};
        float m_i[4], l_i[4];
#pragma unroll
        for (int jj = 0; jj < 4; ++jj) { m_i[jj] = -1e30f; l_i[jj] = 0.0f; }

        f16x8 kreg[3], vreg[3];
#pragma unroll
        for (int p = 0; p < 3; ++p) {
            kreg[p] = *reinterpret_cast<const f16x8*>(
                &qkv[base + (size_t)kkey * 2304 + 768 + 8 * (kc + 4 * p)]);
            vreg[p] = *reinterpret_cast<const f16x8*>(
                &qkv[base + (size_t)vkey * 2304 + 1536 + 8 * (vrow + 4 * p)]);
        }

        for (int kt = 0; kt <= qt; ++kt) {
            __syncthreads();
#pragma unroll
            for (int p = 0; p < 3; ++p)
                *reinterpret_cast<f16x8*>(&Ks[kkey * 104 + 8 * (kc + 4 * p)]) = kreg[p];
#pragma unroll
            for (int p = 0; p < 3; ++p) {
                int dr = 8 * (vrow + 4 * p);
#pragma unroll
                for (int e = 0; e < 8; ++e)
                    Vt[(dr + e) * 72 + vkey] = vreg[p][e];
            }
            __syncthreads();

            if (kt < qt) {
                const int k0n = (kt + 1) * 64;
#pragma unroll
                for (int p = 0; p < 3; ++p) {
                    kreg[p] = *reinterpret_cast<const f16x8*>(
                        &qkv[base + (size_t)(k0n + kkey) * 2304 + 768 + 8 * (kc + 4 * p)]);
                    vreg[p] = *reinterpret_cast<const f16x8*>(
                        &qkv[base + (size_t)(k0n + vkey) * 2304 + 1536 + 8 * (vrow + 4 * p)]);
                }
            }

            f32x4 S[4];
#pragma unroll
            for (int n = 0; n < 4; ++n) {
                f32x4 acc = {};
#pragma unroll
                for (int s = 0; s < 3; ++s) {
                    f16x8 kf = *reinterpret_cast<const f16x8*>(
                        &Ks[(n * 16 + fr) * 104 + s * 32 + fq * 8]);
                    acc = __builtin_amdgcn_mfma_f32_16x16x32_f16(qa[s], kf, acc, 0, 0, 0);
                }
                S[n] = acc;
            }

            const bool diag = (kt == qt);
#pragma unroll
            for (int jj = 0; jj < 4; ++jj) {
                float s0 = S[0][jj] * scale, s1 = S[1][jj] * scale;
                float s2 = S[2][jj] * scale, s3 = S[3][jj] * scale;
                if (diag) {
                    int r = wid * 16 + fq * 4 + jj;
                    if (fr > r)      s0 = -1e30f;
                    if (fr + 16 > r) s1 = -1e30f;
                    if (fr + 32 > r) s2 = -1e30f;
                    if (fr + 48 > r) s3 = -1e30f;
                }
                float mx = fmaxf(fmaxf(s0, s1), fmaxf(s2, s3));
#pragma unroll
                for (int off = 8; off; off >>= 1) mx = fmaxf(mx, __shfl_xor(mx, off, 16));
                float mnew = fmaxf(m_i[jj], mx);
                float sf = __expf(m_i[jj] - mnew);
                m_i[jj] = mnew;
                float p0 = __expf(s0 - mnew), p1 = __expf(s1 - mnew);
                float p2 = __expf(s2 - mnew), p3 = __expf(s3 - mnew);
                float rs = p0 + p1 + p2 + p3;
#pragma unroll
                for (int off = 8; off; off >>= 1) rs += __shfl_xor(rs, off, 16);
                l_i[jj] = l_i[jj] * sf + rs;
                const int prow = wid * 16 + fq * 4 + jj;
                Ps[prow * 72 + fr]      = (_Float16)p0;
                Ps[prow * 72 + 16 + fr] = (_Float16)p1;
                Ps[prow * 72 + 32 + fr] = (_Float16)p2;
                Ps[prow * 72 + 48 + fr] = (_Float16)p3;
#pragma unroll
                for (int n = 0; n < 6; ++n) O[n][jj] *= sf;
            }

#pragma unroll
            for (int ks = 0; ks < 2; ++ks) {
                f16x8 pf = *reinterpret_cast<const f16x8*>(
                    &Ps[(wid * 16 + fr) * 72 + ks * 32 + fq * 8]);
#pragma unroll
                for (int n = 0; n < 6; ++n) {
                    f16x8 vf = *reinterpret_cast<const f16x8*>(
                        &Vt[(n * 16 + fr) * 72 + ks * 32 + fq * 8]);
                    O[n] = __builtin_amdgcn_mfma_f32_16x16x32_f16(pf, vf, O[n], 0, 0, 0);
                }
            }
        }

#pragma unroll
        for (int jj = 0; jj < 4; ++jj) {
            const int q = q0 + wid * 16 + fq * 4 + jj;
            const float invl = 1.0f / l_i[jj];
            _Float16* yr = y + ((size_t)b * TSEQ + q) * CDIM + h * 96;
#pragma unroll
            for (int n = 0; n < 6; ++n)
                yr[n * 16 + fr] = (_Float16)(O[n][jj] * invl);
        }
    }
}

// ---------------- launch ----------------
extern "C" void kernel_launch(void* const* d_in, const int* in_sizes, int n_in,
                              void* d_out, int out_size, void* d_ws, size_t ws_size,
                              hipStream_t stream) {
    const float* x        = (const float*)d_in[0];
    const float* ln1_g    = (const float*)d_in[1];
    const float* ln1_b    = (const float*)d_in[2];
    const float* ln2_g    = (const float*)d_in[3];
    const float* ln2_b    = (const float*)d_in[4];
    const float* W_attn   = (const float*)d_in[5];
    const float* b_attn   = (const float*)d_in[6];
    const float* W_proj   = (const float*)d_in[7];
    const float* b_proj   = (const float*)d_in[8];
    const float* W_fc     = (const float*)d_in[9];
    const float* b_fc     = (const float*)d_in[10];
    const float* W_fcproj = (const float*)d_in[11];
    const float* b_fcproj = (const float*)d_in[12];
    float* out = (float*)d_out;

    _Float16* qkvh  = (_Float16*)d_ws;                       // M*2304
    _Float16* actsh = qkvh + (size_t)MROWS * 2304;           // M*768
    _Float16* hh    = actsh + (size_t)MROWS * CDIM;          // M*3072
    _Float16* wah   = hh + (size_t)MROWS * 3072;             // 2304*768
    _Float16* wph   = wah + (size_t)2304 * 768;              // 768*768
    _Float16* wfh   = wph + (size_t)768 * 768;               // 3072*768
    _Float16* wfph  = wfh + (size_t)3072 * 768;              // 768*3072

    dim3 blk(256);

    f2h4_kernel<<<dim3(1728), blk, 0, stream>>>(W_attn, W_proj, W_fc, W_fcproj,
                                                wah, wph, wfh, wfph);

    ln_kernel<<<dim3(MROWS), blk, 0, stream>>>(x, ln1_g, ln1_b, actsh);
    hgemm<0, _Float16><<<dim3(2304 / 128, MROWS / 128), blk, 0, stream>>>(
        actsh, wah, b_attn, nullptr, qkvh, MROWS, 2304, CDIM);
    attn_kernel<<<dim3(8, 64), blk, 0, stream>>>(qkvh, actsh);
    hgemm64<1, float><<<dim3(CDIM / 128, MROWS / 64), blk, 0, stream>>>(
        actsh, wph, b_proj, x, out, MROWS, CDIM, CDIM);
    ln_kernel<<<dim3(MROWS), blk, 0, stream>>>(out, ln2_g, ln2_b, actsh);
    hgemm<2, _Float16><<<dim3(3072 / 128, MROWS / 128), blk, 0, stream>>>(
        actsh, wfh, b_fc, nullptr, hh, MROWS, 3072, CDIM);
    hgemm64<1, float><<<dim3(CDIM / 128, MROWS / 64), blk, 0, stream>>>(
        hh, wfph, b_fcproj, out, out, MROWS, CDIM, 3072);
}

// Round 10
// 385.735 us; speedup vs baseline: 1.0532x; 1.0532x over previous
//
#include <hip/hip_runtime.h>
#include <math.h>

// GPT-2 block. B=8 T=1024 C=768 H=8 D=96. M = B*T = 8192.
// GEMMs + attention in fp16 MFMA (fp32 accum/softmax), LN/epilogues fp32.
// R10: 2-phase double-buffered GEMM pipeline (T3-minimum): stage(next) issued
//      before compute(cur), ONE barrier per K-step. Halves barrier count and
//      hides global->LDS latency under MFMA.

#define MROWS 8192
#define CDIM  768
#define TSEQ  1024

typedef _Float16 f16x8 __attribute__((ext_vector_type(8)));
typedef _Float16 f16x4 __attribute__((ext_vector_type(4)));
typedef float f32x4 __attribute__((ext_vector_type(4)));

__device__ __forceinline__ void async_copy16(void* lds, const void* g) {
    __builtin_amdgcn_global_load_lds(
        (const __attribute__((address_space(1))) unsigned int*)g,
        (__attribute__((address_space(3))) unsigned int*)lds, 16, 0, 0);
}

// bijective XCD-aware swizzle of the linear workgroup id (m204 form)
__device__ __forceinline__ int xcd_swizzle(int orig, int nwg) {
    int q = nwg >> 3, r = nwg & 7;
    int xcd = orig & 7, lid = orig >> 3;
    return (xcd < r ? xcd * (q + 1) : r * (q + 1) + (xcd - r) * q) + lid;
}

// GELU (tanh form) with tanh(u) = 1 - 2/(exp(2u)+1); exact limits at +-inf.
__device__ __forceinline__ float fast_gelu(float u) {
    float inner = 0.7978845608028654f * (u + 0.044715f * u * u * u);
    float e = __expf(2.0f * inner);
    float th = 1.0f - 2.0f / (e + 1.0f);
    return 0.5f * u * (1.0f + th);
}

// ------------- fused fp32 -> fp16 convert for all 4 weights -------------
__global__ __launch_bounds__(256) void f2h4_kernel(const float* __restrict__ i0,
                                                   const float* __restrict__ i1,
                                                   const float* __restrict__ i2,
                                                   const float* __restrict__ i3,
                                                   _Float16* __restrict__ o0,
                                                   _Float16* __restrict__ o1,
                                                   _Float16* __restrict__ o2,
                                                   _Float16* __restrict__ o3) {
    int bb = blockIdx.x;
    const float* in;
    _Float16* out;
    int lb;
    if (bb < 432)       { in = i0; out = o0; lb = bb; }
    else if (bb < 576)  { in = i1; out = o1; lb = bb - 432; }
    else if (bb < 1152) { in = i2; out = o2; lb = bb - 576; }
    else                { in = i3; out = o3; lb = bb - 1152; }
    int i = lb * 1024 + threadIdx.x;
#pragma unroll
    for (int p = 0; p < 4; ++p, i += 256) {
        float4 v = reinterpret_cast<const float4*>(in)[i];
        f16x4 h;
        h[0] = (_Float16)v.x; h[1] = (_Float16)v.y;
        h[2] = (_Float16)v.z; h[3] = (_Float16)v.w;
        reinterpret_cast<f16x4*>(out)[i] = h;
    }
}

// ---------------- LayerNorm -> fp16 out ----------------
__global__ __launch_bounds__(256) void ln_kernel(const float* __restrict__ x,
                                                 const float* __restrict__ g,
                                                 const float* __restrict__ bta,
                                                 _Float16* __restrict__ out) {
    int row = blockIdx.x;
    int t = threadIdx.x;
    const float* xr = x + (size_t)row * CDIM;
    float v0 = xr[t], v1 = xr[t + 256], v2 = xr[t + 512];
    float s = v0 + v1 + v2;
    float q = v0 * v0 + v1 * v1 + v2 * v2;
#pragma unroll
    for (int o = 32; o; o >>= 1) {
        s += __shfl_xor(s, o);
        q += __shfl_xor(q, o);
    }
    __shared__ float ls[4], lq[4];
    int w = t >> 6, lane = t & 63;
    if (lane == 0) { ls[w] = s; lq[w] = q; }
    __syncthreads();
    s = ls[0] + ls[1] + ls[2] + ls[3];
    q = lq[0] + lq[1] + lq[2] + lq[3];
    float mean = s * (1.0f / CDIM);
    float var = fmaxf(q * (1.0f / CDIM) - mean * mean, 0.0f);
    float rstd = rsqrtf(var + 1e-5f);
    _Float16* orow = out + (size_t)row * CDIM;
    orow[t]       = (_Float16)((v0 - mean) * rstd * g[t]       + bta[t]);
    orow[t + 256] = (_Float16)((v1 - mean) * rstd * g[t + 256] + bta[t + 256]);
    orow[t + 512] = (_Float16)((v2 - mean) * rstd * g[t + 512] + bta[t + 512]);
}

// -------- fp16 MFMA GEMM, BM=128, 2-phase double-buffered pipeline --------
template <int EPI, typename OutT>  // EPI 0: bias, 1: bias+res, 2: bias+gelu
__global__ __launch_bounds__(256) void hgemm(const _Float16* __restrict__ A,
                                             const _Float16* __restrict__ W,
                                             const float* __restrict__ bias,
                                             const float* __restrict__ res,
                                             OutT* __restrict__ out,
                                             int M, int N, int K) {
    __shared__ _Float16 As[2][128 * 32];
    __shared__ _Float16 Bs[2][128 * 32];
    const int t = threadIdx.x;
    const int wid = t >> 6;
    const int l = t & 63;
    const int fr = l & 15;
    const int fq = l >> 4;
    const int wr = wid >> 1, wc = wid & 1;

    const int nx = gridDim.x;
    const int wg = xcd_swizzle(blockIdx.y * nx + blockIdx.x, nx * gridDim.y);
    const int row0 = (wg / nx) * 128, col0 = (wg % nx) * 128;

    const _Float16* ga = A + (size_t)row0 * K;
    const _Float16* gb = W + (size_t)col0 * K;

    f32x4 acc[4][4] = {};
    const int r_st = t >> 2, c_st = (t & 3) * 8;
    const int nt = K >> 5;

    auto stage = [&](int buf, int k0) {
#pragma unroll
        for (int p = 0; p < 2; ++p) {
            char* la = (char*)&As[buf][0] + wid * 1024 + p * 4096;
            char* lb = (char*)&Bs[buf][0] + wid * 1024 + p * 4096;
            int r = r_st + p * 64;
            async_copy16(la, ga + (size_t)r * K + k0 + c_st);
            async_copy16(lb, gb + (size_t)r * K + k0 + c_st);
        }
    };

    auto step = [&](int buf, int tt) {
        if (tt + 1 < nt) stage(buf ^ 1, (tt + 1) << 5);  // next tile in flight
        f16x8 af[4], bf[4];
#pragma unroll
        for (int m = 0; m < 4; ++m)
            af[m] = *reinterpret_cast<const f16x8*>(&As[buf][(wr * 64 + m * 16 + fr) * 32 + fq * 8]);
#pragma unroll
        for (int n = 0; n < 4; ++n)
            bf[n] = *reinterpret_cast<const f16x8*>(&Bs[buf][(wc * 64 + n * 16 + fr) * 32 + fq * 8]);
#pragma unroll
        for (int m = 0; m < 4; ++m)
#pragma unroll
            for (int n = 0; n < 4; ++n)
                acc[m][n] = __builtin_amdgcn_mfma_f32_16x16x32_f16(af[m], bf[n], acc[m][n], 0, 0, 0);
        __syncthreads();  // drains this wave's vmcnt (next tile landed) + read-done
    };

    stage(0, 0);
    __syncthreads();
    for (int tt = 0; tt < nt; tt += 2) {  // nt is even for all call sites
        step(0, tt);
        step(1, tt + 1);
    }

#pragma unroll
    for (int m = 0; m < 4; ++m) {
#pragma unroll
        for (int j = 0; j < 4; ++j) {
            int r = row0 + wr * 64 + m * 16 + fq * 4 + j;
#pragma unroll
            for (int n = 0; n < 4; ++n) {
                int c = col0 + wc * 64 + n * 16 + fr;
                float v = acc[m][n][j] + bias[c];
                if (EPI == 1) v += res[(size_t)r * N + c];
                if (EPI == 2) v = fast_gelu(v);
                out[(size_t)r * N + c] = (OutT)v;
            }
        }
    }
}

// ---- fp16 MFMA GEMM, BM=64 (grid-limited N=768), 2-phase double-buffered ----
template <int EPI, typename OutT>
__global__ __launch_bounds__(256) void hgemm64(const _Float16* __restrict__ A,
                                               const _Float16* __restrict__ W,
                                               const float* __restrict__ bias,
                                               const float* __restrict__ res,
                                               OutT* __restrict__ out,
                                               int M, int N, int K) {
    __shared__ _Float16 As[2][64 * 32];
    __shared__ _Float16 Bs[2][128 * 32];
    const int t = threadIdx.x;
    const int wid = t >> 6;
    const int l = t & 63;
    const int fr = l & 15;
    const int fq = l >> 4;
    const int wr = wid >> 1, wc = wid & 1;

    const int nx = gridDim.x;
    const int wg = xcd_swizzle(blockIdx.y * nx + blockIdx.x, nx * gridDim.y);
    const int row0 = (wg / nx) * 64, col0 = (wg % nx) * 128;

    const _Float16* ga = A + (size_t)row0 * K;
    const _Float16* gb = W + (size_t)col0 * K;

    f32x4 acc[2][4] = {};
    const int rl = l >> 2, cl = (l & 3) * 8;
    const int nt = K >> 5;

    auto stage = [&](int buf, int k0) {
        async_copy16((char*)&As[buf][0] + wid * 1024,
                     ga + (size_t)(wid * 16 + rl) * K + k0 + cl);
#pragma unroll
        for (int p = 0; p < 2; ++p)
            async_copy16((char*)&Bs[buf][0] + wid * 2048 + p * 1024,
                         gb + (size_t)(wid * 32 + p * 16 + rl) * K + k0 + cl);
    };

    auto step = [&](int buf, int tt) {
        if (tt + 1 < nt) stage(buf ^ 1, (tt + 1) << 5);
        f16x8 af[2], bf[4];
#pragma unroll
        for (int m = 0; m < 2; ++m)
            af[m] = *reinterpret_cast<const f16x8*>(&As[buf][(wr * 32 + m * 16 + fr) * 32 + fq * 8]);
#pragma unroll
        for (int n = 0; n < 4; ++n)
            bf[n] = *reinterpret_cast<const f16x8*>(&Bs[buf][(wc * 64 + n * 16 + fr) * 32 + fq * 8]);
#pragma unroll
        for (int m = 0; m < 2; ++m)
#pragma unroll
            for (int n = 0; n < 4; ++n)
                acc[m][n] = __builtin_amdgcn_mfma_f32_16x16x32_f16(af[m], bf[n], acc[m][n], 0, 0, 0);
        __syncthreads();
    };

    stage(0, 0);
    __syncthreads();
    for (int tt = 0; tt < nt; tt += 2) {
        step(0, tt);
        step(1, tt + 1);
    }

#pragma unroll
    for (int m = 0; m < 2; ++m) {
#pragma unroll
        for (int j = 0; j < 4; ++j) {
            int r = row0 + wr * 32 + m * 16 + fq * 4 + j;
#pragma unroll
            for (int n = 0; n < 4; ++n) {
                int c = col0 + wc * 64 + n * 16 + fr;
                float v = acc[m][n][j] + bias[c];
                if (EPI == 1) v += res[(size_t)r * N + c];
                if (EPI == 2) v = fast_gelu(v);
                out[(size_t)r * N + c] = (OutT)v;
            }
        }
    }
}

// ---------------- Flash attention, fp16 MFMA ----------------
__global__ __launch_bounds__(256) void attn_kernel(const _Float16* __restrict__ qkv,
                                                   _Float16* __restrict__ y) {
    const int bx = blockIdx.x;  // 0..7
    const int bh = blockIdx.y;
    const int b = bh >> 3, h = bh & 7;
    const int t = threadIdx.x;
    const int wid = t >> 6, l = t & 63;
    const int fr = l & 15, fq = l >> 4;

    __shared__ _Float16 Ks[64 * 104];
    __shared__ _Float16 Vt[96 * 72];
    __shared__ _Float16 Ps[64 * 72];

    const size_t base = (size_t)b * TSEQ * 2304 + h * 96;
    const float scale = 0.10206207261596577f;  // 1/sqrt(96)

    const int kkey = t >> 2, kc = t & 3;
    const int vkey = l, vrow = wid;

    for (int ph = 0; ph < 2; ++ph) {
        const int qt = ph ? (15 - bx) : bx;
        const int q0 = qt * 64;
        const int qrow_g = q0 + wid * 16 + fr;

        f16x8 qa[3];
#pragma unroll
        for (int s = 0; s < 3; ++s)
            qa[s] = *reinterpret_cast<const f16x8*>(
                &qkv[base + (size_t)qrow_g * 2304 + s * 32 + fq * 8]);

        f32x4 O[6] = {};
        float m_i[4], l_i[4];
#pragma unroll
        for (int jj = 0; jj < 4; ++jj) { m_i[jj] = -1e30f; l_i[jj] = 0.0f; }

        f16x8 kreg[3], vreg[3];
#pragma unroll
        for (int p = 0; p < 3; ++p) {
            kreg[p] = *reinterpret_cast<const f16x8*>(
                &qkv[base + (size_t)kkey * 2304 + 768 + 8 * (kc + 4 * p)]);
            vreg[p] = *reinterpret_cast<const f16x8*>(
                &qkv[base + (size_t)vkey * 2304 + 1536 + 8 * (vrow + 4 * p)]);
        }

        for (int kt = 0; kt <= qt; ++kt) {
            __syncthreads();
#pragma unroll
            for (int p = 0; p < 3; ++p)
                *reinterpret_cast<f16x8*>(&Ks[kkey * 104 + 8 * (kc + 4 * p)]) = kreg[p];
#pragma unroll
            for (int p = 0; p < 3; ++p) {
                int dr = 8 * (vrow + 4 * p);
#pragma unroll
                for (int e = 0; e < 8; ++e)
                    Vt[(dr + e) * 72 + vkey] = vreg[p][e];
            }
            __syncthreads();

            if (kt < qt) {
                const int k0n = (kt + 1) * 64;
#pragma unroll
                for (int p = 0; p < 3; ++p) {
                    kreg[p] = *reinterpret_cast<const f16x8*>(
                        &qkv[base + (size_t)(k0n + kkey) * 2304 + 768 + 8 * (kc + 4 * p)]);
                    vreg[p] = *reinterpret_cast<const f16x8*>(
                        &qkv[base + (size_t)(k0n + vkey) * 2304 + 1536 + 8 * (vrow + 4 * p)]);
                }
            }

            f32x4 S[4];
#pragma unroll
            for (int n = 0; n < 4; ++n) {
                f32x4 acc = {};
#pragma unroll
                for (int s = 0; s < 3; ++s) {
                    f16x8 kf = *reinterpret_cast<const f16x8*>(
                        &Ks[(n * 16 + fr) * 104 + s * 32 + fq * 8]);
                    acc = __builtin_amdgcn_mfma_f32_16x16x32_f16(qa[s], kf, acc, 0, 0, 0);
                }
                S[n] = acc;
            }

            const bool diag = (kt == qt);
#pragma unroll
            for (int jj = 0; jj < 4; ++jj) {
                float s0 = S[0][jj] * scale, s1 = S[1][jj] * scale;
                float s2 = S[2][jj] * scale, s3 = S[3][jj] * scale;
                if (diag) {
                    int r = wid * 16 + fq * 4 + jj;
                    if (fr > r)      s0 = -1e30f;
                    if (fr + 16 > r) s1 = -1e30f;
                    if (fr + 32 > r) s2 = -1e30f;
                    if (fr + 48 > r) s3 = -1e30f;
                }
                float mx = fmaxf(fmaxf(s0, s1), fmaxf(s2, s3));
#pragma unroll
                for (int off = 8; off; off >>= 1) mx = fmaxf(mx, __shfl_xor(mx, off, 16));
                float mnew = fmaxf(m_i[jj], mx);
                float sf = __expf(m_i[jj] - mnew);
                m_i[jj] = mnew;
                float p0 = __expf(s0 - mnew), p1 = __expf(s1 - mnew);
                float p2 = __expf(s2 - mnew), p3 = __expf(s3 - mnew);
                float rs = p0 + p1 + p2 + p3;
#pragma unroll
                for (int off = 8; off; off >>= 1) rs += __shfl_xor(rs, off, 16);
                l_i[jj] = l_i[jj] * sf + rs;
                const int prow = wid * 16 + fq * 4 + jj;
                Ps[prow * 72 + fr]      = (_Float16)p0;
                Ps[prow * 72 + 16 + fr] = (_Float16)p1;
                Ps[prow * 72 + 32 + fr] = (_Float16)p2;
                Ps[prow * 72 + 48 + fr] = (_Float16)p3;
#pragma unroll
                for (int n = 0; n < 6; ++n) O[n][jj] *= sf;
            }

#pragma unroll
            for (int ks = 0; ks < 2; ++ks) {
                f16x8 pf = *reinterpret_cast<const f16x8*>(
                    &Ps[(wid * 16 + fr) * 72 + ks * 32 + fq * 8]);
#pragma unroll
                for (int n = 0; n < 6; ++n) {
                    f16x8 vf = *reinterpret_cast<const f16x8*>(
                        &Vt[(n * 16 + fr) * 72 + ks * 32 + fq * 8]);
                    O[n] = __builtin_amdgcn_mfma_f32_16x16x32_f16(pf, vf, O[n], 0, 0, 0);
                }
            }
        }

#pragma unroll
        for (int jj = 0; jj < 4; ++jj) {
            const int q = q0 + wid * 16 + fq * 4 + jj;
            const float invl = 1.0f / l_i[jj];
            _Float16* yr = y + ((size_t)b * TSEQ + q) * CDIM + h * 96;
#pragma unroll
            for (int n = 0; n < 6; ++n)
                yr[n * 16 + fr] = (_Float16)(O[n][jj] * invl);
        }
    }
}

// ---------------- launch ----------------
extern "C" void kernel_launch(void* const* d_in, const int* in_sizes, int n_in,
                              void* d_out, int out_size, void* d_ws, size_t ws_size,
                              hipStream_t stream) {
    const float* x        = (const float*)d_in[0];
    const float* ln1_g    = (const float*)d_in[1];
    const float* ln1_b    = (const float*)d_in[2];
    const float* ln2_g    = (const float*)d_in[3];
    const float* ln2_b    = (const float*)d_in[4];
    const float* W_attn   = (const float*)d_in[5];
    const float* b_attn   = (const float*)d_in[6];
    const float* W_proj   = (const float*)d_in[7];
    const float* b_proj   = (const float*)d_in[8];
    const float* W_fc     = (const float*)d_in[9];
    const float* b_fc     = (const float*)d_in[10];
    const float* W_fcproj = (const float*)d_in[11];
    const float* b_fcproj = (const float*)d_in[12];
    float* out = (float*)d_out;

    _Float16* qkvh  = (_Float16*)d_ws;                       // M*2304
    _Float16* actsh = qkvh + (size_t)MROWS * 2304;           // M*768
    _Float16* hh    = actsh + (size_t)MROWS * CDIM;          // M*3072
    _Float16* wah   = hh + (size_t)MROWS * 3072;             // 2304*768
    _Float16* wph   = wah + (size_t)2304 * 768;              // 768*768
    _Float16* wfh   = wph + (size_t)768 * 768;               // 3072*768
    _Float16* wfph  = wfh + (size_t)3072 * 768;              // 768*3072

    dim3 blk(256);

    f2h4_kernel<<<dim3(1728), blk, 0, stream>>>(W_attn, W_proj, W_fc, W_fcproj,
                                                wah, wph, wfh, wfph);

    ln_kernel<<<dim3(MROWS), blk, 0, stream>>>(x, ln1_g, ln1_b, actsh);
    hgemm<0, _Float16><<<dim3(2304 / 128, MROWS / 128), blk, 0, stream>>>(
        actsh, wah, b_attn, nullptr, qkvh, MROWS, 2304, CDIM);
    attn_kernel<<<dim3(8, 64), blk, 0, stream>>>(qkvh, actsh);
    hgemm64<1, float><<<dim3(CDIM / 128, MROWS / 64), blk, 0, stream>>>(
        actsh, wph, b_proj, x, out, MROWS, CDIM, CDIM);
    ln_kernel<<<dim3(MROWS), blk, 0, stream>>>(out, ln2_g, ln2_b, actsh);
    hgemm<2, _Float16><<<dim3(3072 / 128, MROWS / 128), blk, 0, stream>>>(
        actsh, wfh, b_fc, nullptr, hh, MROWS, 3072, CDIM);
    hgemm64<1, float><<<dim3(CDIM / 128, MROWS / 64), blk, 0, stream>>>(
        hh, wfph, b_fcproj, out, out, MROWS, CDIM, 3072);
}